// Round 1
// baseline (335.598 us; speedup 1.0000x reference)
//
#include <hip/hip_runtime.h>
#include <hip/hip_bf16.h>

// ---------------------------------------------------------------------------
// Stage2Loss: total = l_surr + 0.3*l_node + 0.1*l_sep
//   l_surr =  mean_{b,e} P[b,i_e,:] @ d_error   @ P[b,j_e,:]   (circuit pairs)
//   l_sep  = -mean_{b,e} P[b,i_e,:] @ d_hw_norm @ P[b,j_e,:]   (cross pairs)
//   l_node = -mean_b sum_l wn[l] * sum_h P[b,l,h] q[h]
// Strategy: per-batch bf16 MFMA GEMM  T_b = P_log[b] @ [d_error | d_hw_norm]
// fused with per-col-tile gathered pair dots. One block per batch.
// ---------------------------------------------------------------------------

typedef __attribute__((ext_vector_type(8))) short short8;
typedef __attribute__((ext_vector_type(4))) float float4_;
typedef __attribute__((ext_vector_type(4))) unsigned int uint4_;
typedef __attribute__((ext_vector_type(2))) unsigned int uint2_;

#define BATCH 512
#define HDIM  256
#define LDIM  200
#define NPAIR 512

// ws float-index layout:
//  [0] S_surr  [1] S_sep  [2] S_node  [3] inv_qi_sum  [4] inv_dhw_max
//  [16..271] q[256]
//  byte 2048: DcatT bf16 [512][256]; row c = Dcat column c
//             (c<256 -> d_error[:,c]; c>=256 -> d_hw[:,c-256]*inv_max)
#define WS_DCAT_BYTE_OFF 2048

__device__ __forceinline__ unsigned short f2b(float f) {  // RNE f32->bf16 (finite inputs)
  unsigned int u = __float_as_uint(f);
  return (unsigned short)((u + 0x7FFFu + ((u >> 16) & 1u)) >> 16);
}
__device__ __forceinline__ float b2f(unsigned short u) {
  return __uint_as_float(((unsigned int)u) << 16);
}

// ------------------------- prep: q, scalars, zero accums --------------------
__global__ void s2l_prep(const float* __restrict__ feat, const float* __restrict__ W1,
                         const float* __restrict__ bias1, const float* __restrict__ W2,
                         const float* __restrict__ bias2, const float* __restrict__ qi,
                         const float* __restrict__ d_hw, float* __restrict__ ws) {
  __shared__ float red[8];
  const int tid = threadIdx.x;  // 256 threads
  // quality_score MLP, one h per thread
  if (tid < 256) {
    float f0 = feat[tid * 5 + 0], f1 = feat[tid * 5 + 1], f2 = feat[tid * 5 + 2];
    float f3 = feat[tid * 5 + 3], f4 = feat[tid * 5 + 4];
    float s = bias2[0];
#pragma unroll
    for (int j = 0; j < 32; ++j) {
      float hd = bias1[j] + f0 * W1[j] + f1 * W1[32 + j] + f2 * W1[64 + j] +
                 f3 * W1[96 + j] + f4 * W1[128 + j];
      hd = fmaxf(hd, 0.f);
      s += hd * W2[j];
    }
    ws[16 + tid] = 1.f / (1.f + expf(-s));
  }
  // qubit_importance sum
  float v = (tid < LDIM) ? qi[tid] : 0.f;
#pragma unroll
  for (int off = 32; off > 0; off >>= 1) v += __shfl_down(v, off);
  if ((tid & 63) == 0) red[tid >> 6] = v;
  __syncthreads();
  if (tid == 0) ws[3] = 1.f / fmaxf(red[0] + red[1] + red[2] + red[3], 1e-8f);
  // d_hw max
  float m = 0.f;
  for (int k = tid; k < HDIM * HDIM; k += 256) m = fmaxf(m, d_hw[k]);
#pragma unroll
  for (int off = 32; off > 0; off >>= 1) m = fmaxf(m, __shfl_down(m, off));
  __syncthreads();  // red[0..3] consumed above before overwrite
  if ((tid & 63) == 0) red[tid >> 6] = m;
  __syncthreads();
  if (tid == 0) {
    float mm = fmaxf(fmaxf(red[0], red[1]), fmaxf(red[2], red[3]));
    ws[4] = 1.f / fmaxf(mm, 1e-8f);
    ws[0] = 0.f; ws[1] = 0.f; ws[2] = 0.f;
  }
}

// ------------------- DcatT build: [512 cols][256 h] bf16 --------------------
__global__ void s2l_dcat(const float* __restrict__ d_err, const float* __restrict__ d_hw,
                         const float* __restrict__ ws, unsigned short* __restrict__ DcatT) {
  const int c = blockIdx.x;   // 0..511 Dcat column
  const int h = threadIdx.x;  // 0..255
  float v = (c < 256) ? d_err[h * 256 + c] : d_hw[h * 256 + (c - 256)] * ws[4];
  DcatT[c * 256 + h] = f2b(v);
}

// ------------------------------- main kernel --------------------------------
// LDS: P 200x256 bf16 (swizzled) | D 64x256 bf16 (swizzled) | T 208x64 bf16 (swizzled)
#define P_OFF 0
#define D_OFF 102400
#define T_OFF 135168
#define LDS_BYTES 161792

__global__ __launch_bounds__(512, 2) void s2l_main(
    const float* __restrict__ P, const int* __restrict__ cpairs,
    const int* __restrict__ xpairs, const float* __restrict__ qi,
    float* __restrict__ ws, const unsigned short* __restrict__ DcatT) {
  __shared__ __attribute__((aligned(16))) unsigned char smem[LDS_BYTES];
  const int tid = threadIdx.x;
  const int wave = tid >> 6, lane = tid & 63;
  const int b = blockIdx.x;
  const int nq = wave >> 1;   // 0..3 : P-row tile quarter (N side)
  const int mg = wave & 1;    // 0..1 : Dcat-col half within 64-col tile (M side)
  const int ncol = lane & 15; // within-tile index
  const int kg = lane >> 4;   // 0..3 k-group

  // --- issue ct=0 D-tile global loads early (latency hidden under P staging)
  uint4_ dreg[4];
#pragma unroll
  for (int it = 0; it < 4; ++it) {
    int sg = it * 512 + tid;  // 0..2047 16B-slots of the 32KB D tile
    dreg[it] = *(const uint4_*)(DcatT + sg * 8);
  }

  // --- per-thread loop-invariant q slice (slot s = tid&31 every iteration)
  const int s0 = (tid & 31) * 8;
  float qreg[8];
#pragma unroll
  for (int e = 0; e < 8; ++e) qreg[e] = ws[16 + s0 + e];
  const float inv_qs = ws[3];

  // --- stage P_log[b] -> bf16 LDS (swizzled) + l_node partial (f32 path)
  const float* Pb = P + (size_t)b * (HDIM * HDIM);
  float lnode = 0.f;
  for (int sg = tid; sg < LDIM * 32; sg += 512) {  // 6400 16B-slots
    int row = sg >> 5, s = sg & 31;
    float4_ a0 = *(const float4_*)(Pb + row * HDIM + s * 8);
    float4_ a1 = *(const float4_*)(Pb + row * HDIM + s * 8 + 4);
    short8 v;
    v[0] = (short)f2b(a0[0]); v[1] = (short)f2b(a0[1]);
    v[2] = (short)f2b(a0[2]); v[3] = (short)f2b(a0[3]);
    v[4] = (short)f2b(a1[0]); v[5] = (short)f2b(a1[1]);
    v[6] = (short)f2b(a1[2]); v[7] = (short)f2b(a1[3]);
    int swz = (s & 24) | ((s & 7) ^ (row & 7));
    *(short8*)(smem + P_OFF + row * 512 + swz * 16) = v;
    float vq = a0[0] * qreg[0] + a0[1] * qreg[1] + a0[2] * qreg[2] + a0[3] * qreg[3] +
               a1[0] * qreg[4] + a1[1] * qreg[5] + a1[2] * qreg[6] + a1[3] * qreg[7];
    lnode += vq * (qi[row] * inv_qs);
  }
  // --- write ct=0 D tile (swizzled)
#pragma unroll
  for (int it = 0; it < 4; ++it) {
    int sg = it * 512 + tid, r = sg >> 5, s = sg & 31;
    int swz = (s & 24) | ((s & 7) ^ (r & 7));
    *(uint4_*)(smem + D_OFF + r * 512 + swz * 16) = dreg[it];
  }
  __syncthreads();

  // --- register-resident P fragments (B operand): 4 N-tiles x 8 k-steps
  short8 pf[4][8];
#pragma unroll
  for (int nt = 0; nt < 4; ++nt) {
    int tileN = nq * 4 + nt;
    if (tileN < 13) {
      int prow = tileN * 16 + ncol;  // rows 200..207 read harmless finite garbage
#pragma unroll
      for (int ks = 0; ks < 8; ++ks) {
        int slot = ks * 4 + kg;
        int swz = (slot & 24) | ((slot & 7) ^ (prow & 7));
        pf[nt][ks] = *(const short8*)(smem + P_OFF + prow * 512 + swz * 16);
      }
    } else {
      short8 z = {0, 0, 0, 0, 0, 0, 0, 0};
#pragma unroll
      for (int ks = 0; ks < 8; ++ks) pf[nt][ks] = z;
    }
  }

  // --- pair indices resident
  const int ic = cpairs[2 * tid], jc = cpairs[2 * tid + 1];
  const int ix = xpairs[2 * tid], jx = xpairs[2 * tid + 1];

  float s_surr = 0.f, s_sep = 0.f;
#pragma unroll 1
  for (int ct = 0; ct < 8; ++ct) {
    // ---- MFMA: T[prow][kcol] = sum_h Dcat[h][ct*64+kcol] * P[prow][h]
    // operands swapped: A = Dcat-col frags, B = P-row frags -> C gives 4
    // consecutive kcols per lane (b64 T-writes).
    float4_ acc[4][2];
#pragma unroll
    for (int nt = 0; nt < 4; ++nt)
#pragma unroll
      for (int mt = 0; mt < 2; ++mt) acc[nt][mt] = (float4_){0.f, 0.f, 0.f, 0.f};
#pragma unroll
    for (int ks = 0; ks < 8; ++ks) {
      short8 af[2];
#pragma unroll
      for (int mt = 0; mt < 2; ++mt) {
        int colL = mg * 32 + mt * 16 + ncol;
        int slot = ks * 4 + kg;
        int swz = (slot & 24) | ((slot & 7) ^ (colL & 7));
        af[mt] = *(const short8*)(smem + D_OFF + colL * 512 + swz * 16);
      }
#pragma unroll
      for (int nt = 0; nt < 4; ++nt)
#pragma unroll
        for (int mt = 0; mt < 2; ++mt)
          acc[nt][mt] = __builtin_amdgcn_mfma_f32_16x16x32_bf16(af[mt], pf[nt][ks],
                                                                acc[nt][mt], 0, 0, 0);
    }
    // ---- T writes: lane holds kcol = mg*32+mt*16+kg*4 + reg (4 consecutive)
#pragma unroll
    for (int nt = 0; nt < 4; ++nt) {
      int tileN = nq * 4 + nt;
      if (tileN >= 13) continue;  // wave-uniform
      int prow = tileN * 16 + ncol;
#pragma unroll
      for (int mt = 0; mt < 2; ++mt) {
        uint2_ pk;
        pk[0] = (unsigned int)f2b(acc[nt][mt][0]) | ((unsigned int)f2b(acc[nt][mt][1]) << 16);
        pk[1] = (unsigned int)f2b(acc[nt][mt][2]) | ((unsigned int)f2b(acc[nt][mt][3]) << 16);
        int byteInRow = (mg * 32 + mt * 16 + kg * 4) * 2;
        int slot = byteInRow >> 4, off8 = byteInRow & 15;
        *(uint2_*)(smem + T_OFF + prow * 128 + ((slot ^ (prow & 7)) << 4) + off8) = pk;
      }
    }
    __syncthreads();  // T visible; all D reads done

    // ---- prefetch next D tile into registers (overlaps gather)
    uint4_ dnext[4];
    if (ct < 7) {
#pragma unroll
      for (int it = 0; it < 4; ++it) {
        int sg = it * 512 + tid;
        dnext[it] = *(const uint4_*)(DcatT + (size_t)(ct + 1) * 16384 + sg * 8);
      }
    }
    // ---- gather: thread = pair; 64-col partial dot
    {
      const int i = (ct < 4) ? ic : ix;
      const int j = (ct < 4) ? jc : jx;
      const int pb8 = (ct & 3) * 8;
      float g = 0.f;
#pragma unroll
      for (int s = 0; s < 8; ++s) {
        short8 tv = *(const short8*)(smem + T_OFF + i * 128 + ((s ^ (i & 7)) << 4));
        short8 pv = *(const short8*)(smem + P_OFF + j * 512 + ((pb8 + (s ^ (j & 7))) << 4));
#pragma unroll
        for (int e = 0; e < 8; ++e)
          g += b2f((unsigned short)tv[e]) * b2f((unsigned short)pv[e]);
      }
      if (ct < 4) s_surr += g; else s_sep += g;
    }
    // ---- write next D tile (D region free after mid-loop barrier)
    if (ct < 7) {
#pragma unroll
      for (int it = 0; it < 4; ++it) {
        int sg = it * 512 + tid, r = sg >> 5, s = sg & 31;
        int swz = (s & 24) | ((s & 7) ^ (r & 7));
        *(uint4_*)(smem + D_OFF + r * 512 + swz * 16) = dnext[it];
      }
    }
    __syncthreads();  // D staged + all T/P reads done before next iteration
  }

  // ---- block reduction + atomics
#pragma unroll
  for (int off = 32; off > 0; off >>= 1) {
    s_surr += __shfl_down(s_surr, off);
    s_sep  += __shfl_down(s_sep, off);
    lnode  += __shfl_down(lnode, off);
  }
  float* red = (float*)(smem + D_OFF);  // D region reused as scratch
  if (lane == 0) { red[wave * 3] = s_surr; red[wave * 3 + 1] = s_sep; red[wave * 3 + 2] = lnode; }
  __syncthreads();
  if (tid == 0) {
    float a = 0.f, c = 0.f, d = 0.f;
    for (int w = 0; w < 8; ++w) { a += red[w * 3]; c += red[w * 3 + 1]; d += red[w * 3 + 2]; }
    atomicAdd(&ws[0], a);
    atomicAdd(&ws[1], c);
    atomicAdd(&ws[2], d);
  }
}

// ------------------------------ final combine -------------------------------
__global__ void s2l_final(const float* __restrict__ ws, float* __restrict__ out) {
  if (threadIdx.x == 0) {
    const float inv_be = 1.f / (512.f * 512.f);
    float l_surr = ws[0] * inv_be;
    float l_sep = -ws[1] * inv_be;
    float l_node = -ws[2] / 512.f;
    out[0] = l_surr + 0.3f * l_node + 0.1f * l_sep;
    out[1] = l_surr;
    out[2] = l_node;
    out[3] = l_sep;
  }
}

extern "C" void kernel_launch(void* const* d_in, const int* in_sizes, int n_in,
                              void* d_out, int out_size, void* d_ws, size_t ws_size,
                              hipStream_t stream) {
  (void)in_sizes; (void)n_in; (void)out_size; (void)ws_size;
  const float* P     = (const float*)d_in[0];
  const float* d_err = (const float*)d_in[1];
  const float* d_hw  = (const float*)d_in[2];
  const float* feat  = (const float*)d_in[3];
  const float* qi    = (const float*)d_in[4];
  const float* W1    = (const float*)d_in[5];
  const float* bias1 = (const float*)d_in[6];
  const float* W2    = (const float*)d_in[7];
  const float* bias2 = (const float*)d_in[8];
  const int* cpairs  = (const int*)d_in[9];
  const int* xpairs  = (const int*)d_in[10];
  float* ws = (float*)d_ws;
  unsigned short* DcatT = (unsigned short*)((char*)d_ws + WS_DCAT_BYTE_OFF);
  float* out = (float*)d_out;

  s2l_prep<<<dim3(1), dim3(256), 0, stream>>>(feat, W1, bias1, W2, bias2, qi, d_hw, ws);
  s2l_dcat<<<dim3(512), dim3(256), 0, stream>>>(d_err, d_hw, ws, DcatT);
  s2l_main<<<dim3(512), dim3(512), 0, stream>>>(P, cpairs, xpairs, qi, ws, DcatT);
  s2l_final<<<dim3(1), dim3(64), 0, stream>>>(ws, out);
}